// Round 9
// baseline (558.875 us; speedup 1.0000x reference)
//
#include <hip/hip_runtime.h>

#define NHEADS 16
#define HD 128
#define LSEQ 2048
#define NBATCH 2
#define HDIM 2048
#define NQKV 6144
#define SCALE 0.08838834764831845f

typedef __attribute__((ext_vector_type(8))) short bfx8;
typedef __attribute__((ext_vector_type(4))) short bfx4;
typedef __attribute__((ext_vector_type(4))) float f32x4;

__device__ __forceinline__ unsigned short f2bf(float x) {
  unsigned u = __float_as_uint(x);
  u += 0x7fffu + ((u >> 16) & 1u);
  return (unsigned short)(u >> 16);
}
__device__ __forceinline__ float bf2f(unsigned short u) {
  return __uint_as_float(((unsigned)u) << 16);
}
__device__ __forceinline__ void gload_lds16(const void* g, void* l) {
  __builtin_amdgcn_global_load_lds(
      (const __attribute__((address_space(1))) unsigned int*)g,
      (__attribute__((address_space(3))) unsigned int*)l, 16, 0, 0);
}

// ---------------- cast f32 -> bf16 (vectorized) ----------------
__global__ __launch_bounds__(256) void cast_bf16_kernel(
    const float* __restrict__ in, unsigned short* __restrict__ out, int n4) {
  int i = blockIdx.x * 256 + threadIdx.x;
  if (i >= n4) return;
  float4 v = ((const float4*)in)[i];
  bfx4 o;
  o[0] = (short)f2bf(v.x);
  o[1] = (short)f2bf(v.y);
  o[2] = (short)f2bf(v.z);
  o[3] = (short)f2bf(v.w);
  ((bfx4*)out)[i] = o;
}

// ---------------- L2/L3-direct register GEMM (no LDS, no barriers) ----------------
// C[M,N] = A[M,K] * B[N,K]^T, both operands L3-resident (A 17 MB, B <= 25 MB).
// 4 waves/block (2M x 2N), per-wave 64 x WN output, BK=64 K-steps.
// Per tile/wave: 8 A-frag + 2*NF B-frag global b128 loads (L2-hit), 8*NF MFMAs.
// No synchronization at all: compiler pipelines, co-resident waves cover latency.
template<int WN, bool BF16OUT>
__global__ __launch_bounds__(256, 2) void gemm_flat_kernel(
    const unsigned short* __restrict__ A, const unsigned short* __restrict__ B,
    void* __restrict__ Cout, int M, int N, int K) {
  constexpr int NF = WN / 16;
  constexpr int BN = 2 * WN;
  const int tid = threadIdx.x;
  const int w = tid >> 6, lane = tid & 63;
  const int g = lane >> 4, ln = lane & 15;
  const int nnt = N / BN;
  const int nwg = (M >> 7) * nnt;
  const int bid = blockIdx.x;
  const int swz = (bid & 7) * (nwg >> 3) + (bid >> 3);  // nwg % 8 == 0
  const int bm = (swz / nnt) * 128, bn = (swz % nnt) * BN;
  const int rowA = bm + (w >> 1) * 64 + ln;
  const int colB = bn + (w & 1) * WN + ln;
  const unsigned short* pA = A + (size_t)rowA * K + g * 8;
  const unsigned short* pB = B + (size_t)colB * K + g * 8;

  f32x4 acc[4][NF];
#pragma unroll
  for (int i = 0; i < 4; ++i)
#pragma unroll
    for (int j = 0; j < NF; ++j) acc[i][j] = (f32x4){0.f, 0.f, 0.f, 0.f};

  for (int k0 = 0; k0 < K; k0 += 64) {
    bfx8 a[4][2], b[NF][2];
#pragma unroll
    for (int mf = 0; mf < 4; ++mf)
#pragma unroll
      for (int kk = 0; kk < 2; ++kk)
        a[mf][kk] = *(const bfx8*)(pA + (size_t)mf * 16 * K + k0 + kk * 32);
#pragma unroll
    for (int nf = 0; nf < NF; ++nf)
#pragma unroll
      for (int kk = 0; kk < 2; ++kk)
        b[nf][kk] = *(const bfx8*)(pB + (size_t)nf * 16 * K + k0 + kk * 32);
#pragma unroll
    for (int kk = 0; kk < 2; ++kk)
#pragma unroll
      for (int mf = 0; mf < 4; ++mf)
#pragma unroll
        for (int nf = 0; nf < NF; ++nf)
          acc[mf][nf] = __builtin_amdgcn_mfma_f32_16x16x32_bf16(
              a[mf][kk], b[nf][kk], acc[mf][nf], 0, 0, 0);
  }

#pragma unroll
  for (int mf = 0; mf < 4; ++mf) {
    int row0 = bm + (w >> 1) * 64 + mf * 16 + g * 4;
#pragma unroll
    for (int nf = 0; nf < NF; ++nf) {
      int col = bn + (w & 1) * WN + nf * 16 + ln;
#pragma unroll
      for (int r = 0; r < 4; ++r) {
        if constexpr (BF16OUT)
          ((unsigned short*)Cout)[(size_t)(row0 + r) * N + col] = f2bf(acc[mf][nf][r]);
        else
          ((float*)Cout)[(size_t)(row0 + r) * N + col] = acc[mf][nf][r];
      }
    }
  }
}

// ---------------- RoPE + scatter ----------------
__global__ __launch_bounds__(256) void rope_scatter_kernel(
    const unsigned short* __restrict__ qkv,
    unsigned short* __restrict__ Qo, unsigned short* __restrict__ Ko,
    unsigned short* __restrict__ Vt) {
  __shared__ unsigned short lV[32 * 128];
  const int bh = blockIdx.x;
  const int l0 = blockIdx.y * 32;
  const int b = bh >> 4, h = bh & 15;
  const int tid = threadIdx.x;
#pragma unroll
  for (int it = 0; it < 2; ++it) {
    int idx = it * 256 + tid;
    int ll = idx >> 4;
    int dq = idx & 15;
    int l = l0 + ll;
    const unsigned short* row = qkv + (size_t)(b * LSEQ + l) * NQKV + h * HD;
    bfx4 qlo = *(const bfx4*)(row + dq * 4);
    bfx4 qhi = *(const bfx4*)(row + 64 + dq * 4);
    bfx4 klo = *(const bfx4*)(row + 2048 + dq * 4);
    bfx4 khi = *(const bfx4*)(row + 2048 + 64 + dq * 4);
    bfx4 vlo = *(const bfx4*)(row + 4096 + dq * 4);
    bfx4 vhi = *(const bfx4*)(row + 4096 + 64 + dq * 4);
    bfx4 oqlo, oqhi, oklo, okhi;
#pragma unroll
    for (int e = 0; e < 4; ++e) {
      int d2 = dq * 4 + e;
      float invf = exp2f(-(float)d2 * 0.2076205059304601f);
      float fr = (float)l * invf;
      float s, c;
      sincosf(fr, &s, &c);
      float xq1 = bf2f((unsigned short)qlo[e]), xq2 = bf2f((unsigned short)qhi[e]);
      oqlo[e] = (short)f2bf(xq1 * c - xq2 * s);
      oqhi[e] = (short)f2bf(xq2 * c + xq1 * s);
      float xk1 = bf2f((unsigned short)klo[e]), xk2 = bf2f((unsigned short)khi[e]);
      oklo[e] = (short)f2bf(xk1 * c - xk2 * s);
      okhi[e] = (short)f2bf(xk2 * c + xk1 * s);
    }
    size_t obase = ((size_t)bh * LSEQ + l) * HD;
    *(bfx4*)(Qo + obase + dq * 4) = oqlo;
    *(bfx4*)(Qo + obase + 64 + dq * 4) = oqhi;
    *(bfx4*)(Ko + obase + dq * 4) = oklo;
    *(bfx4*)(Ko + obase + 64 + dq * 4) = okhi;
    *(bfx4*)(lV + ll * 128 + dq * 4) = vlo;
    *(bfx4*)(lV + ll * 128 + 64 + dq * 4) = vhi;
  }
  __syncthreads();
#pragma unroll
  for (int it = 0; it < 16; ++it) {
    int idx = it * 256 + tid;
    int d = idx >> 5;
    int ll = idx & 31;
    Vt[((size_t)bh * HD + d) * LSEQ + l0 + ll] = lV[ll * 128 + d];
  }
}

// ---------------- Flash attention: 8 waves, q-tile 128, KV chunk 64, LDS-staged ----------------
__global__ __launch_bounds__(512, 4) void flash_kernel(
    const unsigned short* __restrict__ Q, const unsigned short* __restrict__ K,
    const unsigned short* __restrict__ Vt, unsigned short* __restrict__ O) {
  __shared__ unsigned short lKs[2][64 * 128];
  __shared__ unsigned short lVs[2][128 * 64];
  __shared__ unsigned short lP[8][16 * 40];
  const int bh = blockIdx.x;
  const int qt = 15 - (int)blockIdx.y;
  const int q0 = qt * 128;
  const int tid = threadIdx.x;
  const int w = tid >> 6, lane = tid & 63;
  const int g = lane >> 4, ln = lane & 15;
  const int q0w = q0 + w * 16;
  const unsigned short* Qb = Q + (size_t)bh * LSEQ * HD;
  const unsigned short* Kb = K + (size_t)bh * LSEQ * HD;
  const unsigned short* Vb = Vt + (size_t)bh * HD * LSEQ;
  unsigned short* Pw = lP[w];

  auto STAGE = [&](int buf, int kv0s) {
#pragma unroll
    for (int s = 0; s < 2; ++s) {
      int rl = s * 32 + w * 4 + (lane >> 4);
      int slot = lane & 15;
      const unsigned short* src =
          Kb + (size_t)(kv0s + rl) * HD + ((slot ^ (rl & 15)) * 8);
      gload_lds16(src, &lKs[buf][(s * 8192 + w * 1024) / 2]);
    }
#pragma unroll
    for (int s = 0; s < 2; ++s) {
      int d = s * 64 + w * 8 + (lane >> 3);
      int slot = lane & 7;
      const unsigned short* src =
          Vb + (size_t)d * LSEQ + kv0s + ((slot ^ (d & 7)) * 8);
      gload_lds16(src, &lVs[buf][(s * 8192 + w * 1024) / 2]);
    }
  };

  bfx8 qf[4];
#pragma unroll
  for (int c = 0; c < 4; ++c)
    qf[c] = *(const bfx8*)(Qb + (size_t)(q0w + ln) * HD + c * 32 + g * 8);

  f32x4 o[8];
#pragma unroll
  for (int dt = 0; dt < 8; ++dt) o[dt] = (f32x4){0.f, 0.f, 0.f, 0.f};
  float m = -1e30f, sum = 0.f;
  const int qg = q0w + ln;
  const int nch = 2 * qt + 2;

  STAGE(0, 0);
  __syncthreads();

  for (int ch = 0; ch < nch; ++ch) {
    const int kv0 = ch * 64;
    const int cur = ch & 1;
    if (ch + 1 < nch) STAGE(cur ^ 1, kv0 + 64);

    if (kv0 <= q0w + 15) {
      const char* lK0 = (const char*)lKs[cur];
      const char* lV0 = (const char*)lVs[cur];
      f32x4 s4[4];
#pragma unroll
      for (int kt = 0; kt < 4; ++kt) s4[kt] = (f32x4){0.f, 0.f, 0.f, 0.f};
#pragma unroll
      for (int c = 0; c < 4; ++c) {
        const int cbb = c * 64 + g * 16;
#pragma unroll
        for (int kt = 0; kt < 4; ++kt) {
          bfx8 kf = *(const bfx8*)(lK0 + (kt * 16 + ln) * 256 + (cbb ^ (ln << 4)));
          s4[kt] = __builtin_amdgcn_mfma_f32_16x16x32_bf16(kf, qf[c], s4[kt], 0, 0, 0);
        }
      }
      float tm = -1e30f;
      if (kv0 + 63 <= q0w) {
#pragma unroll
        for (int kt = 0; kt < 4; ++kt)
#pragma unroll
          for (int r = 0; r < 4; ++r) {
            s4[kt][r] *= SCALE;
            tm = fmaxf(tm, s4[kt][r]);
          }
      } else {
#pragma unroll
        for (int kt = 0; kt < 4; ++kt)
#pragma unroll
          for (int r = 0; r < 4; ++r) {
            int kvr = kv0 + kt * 16 + 4 * g + r;
            float v = (kvr <= qg) ? s4[kt][r] * SCALE : -1e30f;
            s4[kt][r] = v;
            tm = fmaxf(tm, v);
          }
      }
      tm = fmaxf(tm, __shfl_xor(tm, 16));
      tm = fmaxf(tm, __shfl_xor(tm, 32));
      float f = 1.f;
      const bool dorescale = !__all(tm <= m + 8.f);
      if (dorescale) {
        float mnew = fmaxf(m, tm);
        f = __expf(m - mnew);
        m = mnew;
      }
      float ts = 0.f;
      bfx4 pb4[4];
#pragma unroll
      for (int kt = 0; kt < 4; ++kt)
#pragma unroll
        for (int r = 0; r < 4; ++r) {
          float p = __expf(s4[kt][r] - m);
          ts += p;
          pb4[kt][r] = (short)f2bf(p);
        }
      ts += __shfl_xor(ts, 16);
      ts += __shfl_xor(ts, 32);
      sum = sum * f + ts;
      float fr0 = 1.f, fr1 = 1.f, fr2 = 1.f, fr3 = 1.f;
      if (dorescale) {
        fr0 = __shfl(f, 4 * g + 0);
        fr1 = __shfl(f, 4 * g + 1);
        fr2 = __shfl(f, 4 * g + 2);
        fr3 = __shfl(f, 4 * g + 3);
      }
#pragma unroll
      for (int kvh = 0; kvh < 2; ++kvh) {
        asm volatile("s_waitcnt lgkmcnt(0)" ::: "memory");
        __builtin_amdgcn_sched_barrier(0);
        *(bfx4*)(Pw + ln * 40 + 4 * g) = pb4[2 * kvh];
        *(bfx4*)(Pw + ln * 40 + 16 + 4 * g) = pb4[2 * kvh + 1];
        asm volatile("s_waitcnt lgkmcnt(0)" ::: "memory");
        __builtin_amdgcn_sched_barrier(0);
        bfx8 pf = *(const bfx8*)(Pw + ln * 40 + g * 8);
        if (kvh == 0 && dorescale) {
#pragma unroll
          for (int dt = 0; dt < 8; ++dt) {
            o[dt][0] *= fr0; o[dt][1] *= fr1; o[dt][2] *= fr2; o[dt][3] *= fr3;
          }
        }
#pragma unroll
        for (int dt = 0; dt < 8; ++dt) {
          bfx8 vf = *(const bfx8*)(lV0 + (dt * 16 + ln) * 128 +
                                   ((kvh * 64 + g * 16) ^ ((ln & 7) << 4)));
          o[dt] = __builtin_amdgcn_mfma_f32_16x16x32_bf16(pf, vf, o[dt], 0, 0, 0);
        }
      }
    }
    __syncthreads();
  }

  float inv = 1.f / sum;
  float ir0 = __shfl(inv, 4 * g + 0);
  float ir1 = __shfl(inv, 4 * g + 1);
  float ir2 = __shfl(inv, 4 * g + 2);
  float ir3 = __shfl(inv, 4 * g + 3);
  const int b = bh >> 4, h = bh & 15;
  unsigned short* Ob = O + (size_t)b * LSEQ * HDIM + h * HD;
#pragma unroll
  for (int dt = 0; dt < 8; ++dt) {
    Ob[(size_t)(q0w + 4 * g + 0) * HDIM + dt * 16 + ln] = f2bf(o[dt][0] * ir0);
    Ob[(size_t)(q0w + 4 * g + 1) * HDIM + dt * 16 + ln] = f2bf(o[dt][1] * ir1);
    Ob[(size_t)(q0w + 4 * g + 2) * HDIM + dt * 16 + ln] = f2bf(o[dt][2] * ir2);
    Ob[(size_t)(q0w + 4 * g + 3) * HDIM + dt * 16 + ln] = f2bf(o[dt][3] * ir3);
  }
}

// ---------------- launch ----------------
extern "C" void kernel_launch(void* const* d_in, const int* in_sizes, int n_in,
                              void* d_out, int out_size, void* d_ws, size_t ws_size,
                              hipStream_t stream) {
  const float* x = (const float*)d_in[0];
  const float* w_qkv = (const float*)d_in[1];
  const float* w_o = (const float*)d_in[2];
  float* out = (float*)d_out;
  char* ws = (char*)d_ws;

  unsigned short* xb    = (unsigned short*)(ws + 0);
  unsigned short* wqkvb = (unsigned short*)(ws + 16777216);
  unsigned short* wob   = (unsigned short*)(ws + 41943040);
  unsigned short* qkvb  = (unsigned short*)(ws + 50331648);
  unsigned short* qb    = (unsigned short*)(ws + 100663296);
  unsigned short* kb    = (unsigned short*)(ws + 117440512);
  unsigned short* vtb   = (unsigned short*)(ws + 134217728);
  unsigned short* attnb = (unsigned short*)(ws + 0);

  cast_bf16_kernel<<<8388608 / 4 / 256, 256, 0, stream>>>(x, xb, 8388608 / 4);
  cast_bf16_kernel<<<12582912 / 4 / 256, 256, 0, stream>>>(w_qkv, wqkvb, 12582912 / 4);
  cast_bf16_kernel<<<4194304 / 4 / 256, 256, 0, stream>>>(w_o, wob, 4194304 / 4);

  // QKV: 128x192 blocks -> 32*32 = 1024 blocks (2 rounds at 2 blocks/CU)
  gemm_flat_kernel<96, true><<<(4096 / 128) * (6144 / 192), 256, 0, stream>>>(
      xb, wqkvb, (void*)qkvb, 4096, 6144, 2048);

  rope_scatter_kernel<<<dim3(32, 64), 256, 0, stream>>>(qkvb, qb, kb, vtb);

  flash_kernel<<<dim3(32, 16), 512, 0, stream>>>(qb, kb, vtb, attnb);

  // out-proj: 128x128 blocks -> 32*16 = 512 blocks
  gemm_flat_kernel<64, false><<<(4096 / 128) * (2048 / 128), 256, 0, stream>>>(
      attnb, wob, (void*)out, 4096, 2048, 2048);
}

// Round 10
// 435.268 us; speedup vs baseline: 1.2840x; 1.2840x over previous
//
#include <hip/hip_runtime.h>

#define NHEADS 16
#define HD 128
#define LSEQ 2048
#define NBATCH 2
#define HDIM 2048
#define NQKV 6144
#define SCALE 0.08838834764831845f

typedef __attribute__((ext_vector_type(8))) short bfx8;
typedef __attribute__((ext_vector_type(4))) short bfx4;
typedef __attribute__((ext_vector_type(4))) float f32x4;

__device__ __forceinline__ unsigned short f2bf(float x) {
  unsigned u = __float_as_uint(x);
  u += 0x7fffu + ((u >> 16) & 1u);
  return (unsigned short)(u >> 16);
}
__device__ __forceinline__ float bf2f(unsigned short u) {
  return __uint_as_float(((unsigned)u) << 16);
}
__device__ __forceinline__ void gload_lds16(const void* g, void* l) {
  __builtin_amdgcn_global_load_lds(
      (const __attribute__((address_space(1))) unsigned int*)g,
      (__attribute__((address_space(3))) unsigned int*)l, 16, 0, 0);
}

// ---------------- cast f32 -> bf16 (vectorized) ----------------
__global__ __launch_bounds__(256) void cast_bf16_kernel(
    const float* __restrict__ in, unsigned short* __restrict__ out, int n4) {
  int i = blockIdx.x * 256 + threadIdx.x;
  if (i >= n4) return;
  float4 v = ((const float4*)in)[i];
  bfx4 o;
  o[0] = (short)f2bf(v.x);
  o[1] = (short)f2bf(v.y);
  o[2] = (short)f2bf(v.z);
  o[3] = (short)f2bf(v.w);
  ((bfx4*)out)[i] = o;
}

// ---------------- Hybrid GEMM: A via LDS (4x reuse), B global-direct (2x reuse) ----------------
// C[M,N] = A[M,K] * B[N,K]^T. Tile 256 x (2*WNF*16), BK=64, 8 waves (4M x 2N),
// wave-tile 64 x WNF*16. Per tile: 4 A-stage gload_lds + 8 A ds_reads/wave +
// 2*WNF B global b128/wave (L2/L3-served) + 8*WNF MFMA/wave. Barrier-light:
// one vmcnt(0)+s_barrier per K-tile (A-stages issued first => a full tile to land).
template<int WNF, bool BF16OUT>
__global__ __launch_bounds__(512, 1) void gemm_hyb_kernel(
    const unsigned short* __restrict__ A, const unsigned short* __restrict__ B,
    void* __restrict__ Cout, int M, int N, int K) {
  constexpr int WN = WNF * 16;
  constexpr int BN = 2 * WN;
  __shared__ unsigned short lA[2][256 * 64];
  const int tid = threadIdx.x;
  const int w = tid >> 6, lane = tid & 63;
  const int g = lane >> 4, ln = lane & 15;
  const int nmt = M >> 8, nnt = N / BN;
  const int nwg = nmt * nnt;
  const int bid = blockIdx.x;
  const int swz = (bid & 7) * (nwg >> 3) + (bid >> 3);  // nwg % 8 == 0
  const int bm = (swz / nnt) * 256, bn = (swz % nnt) * BN;
  const int wm = (w & 3) * 64;        // 4 M-splits -> dup_A = 2
  const int wn = (w >> 2) * WN;       // 2 N-splits
  const unsigned short* At = A + (size_t)bm * K;
  const unsigned short* pB = B + (size_t)(bn + wn + ln) * K + g * 8;

  auto STG_A = [&](int buf, int q, int k0) {
    int rid = q * 64 + w * 8 + (lane >> 3);
    int slot = lane & 7;
    gload_lds16(At + (size_t)rid * K + k0 + ((slot ^ (rid & 7)) << 3),
                lA[buf] + q * 4096 + w * 512);
  };

  f32x4 acc[4][WNF];
#pragma unroll
  for (int i = 0; i < 4; ++i)
#pragma unroll
    for (int j = 0; j < WNF; ++j) acc[i][j] = (f32x4){0.f, 0.f, 0.f, 0.f};

#pragma unroll
  for (int q = 0; q < 4; ++q) STG_A(0, q, 0);
  asm volatile("s_waitcnt vmcnt(0)" ::: "memory");
  __builtin_amdgcn_s_barrier();

  const int nt = K >> 6;
  for (int t = 0; t < nt; ++t) {
    const int cur = t & 1;
    const char* lAc = (const char*)lA[cur];
    const int k0 = t << 6;
    const bool more = (t + 1 < nt);
    if (more) {
#pragma unroll
      for (int q = 0; q < 4; ++q) STG_A(cur ^ 1, q, k0 + 64);
    }
    // A fragments for this wave's 64 rows (8 ds_read_b128)
    bfx8 a[4][2];
#pragma unroll
    for (int mf = 0; mf < 4; ++mf)
#pragma unroll
      for (int kk = 0; kk < 2; ++kk)
        a[mf][kk] = *(const bfx8*)(lAc + (wm + mf * 16 + ln) * 128 +
                                   (((kk * 4 + g) ^ (ln & 7)) << 4));
    // nf-outer: 2 global B loads feed 8 MFMAs; compiler pipelines the 6 pairs
#pragma unroll
    for (int nf = 0; nf < WNF; ++nf) {
      bfx8 b0 = *(const bfx8*)(pB + (size_t)nf * 16 * K + k0);
      bfx8 b1 = *(const bfx8*)(pB + (size_t)nf * 16 * K + k0 + 32);
#pragma unroll
      for (int mf = 0; mf < 4; ++mf) {
        acc[mf][nf] = __builtin_amdgcn_mfma_f32_16x16x32_bf16(a[mf][0], b0, acc[mf][nf], 0, 0, 0);
        acc[mf][nf] = __builtin_amdgcn_mfma_f32_16x16x32_bf16(a[mf][1], b1, acc[mf][nf], 0, 0, 0);
      }
    }
    asm volatile("s_waitcnt vmcnt(0)" ::: "memory");
    __builtin_amdgcn_s_barrier();
  }

#pragma unroll
  for (int mf = 0; mf < 4; ++mf) {
    int row0 = bm + wm + mf * 16 + g * 4;
#pragma unroll
    for (int nf = 0; nf < WNF; ++nf) {
      int col = bn + wn + nf * 16 + ln;
#pragma unroll
      for (int r = 0; r < 4; ++r) {
        if constexpr (BF16OUT)
          ((unsigned short*)Cout)[(size_t)(row0 + r) * N + col] = f2bf(acc[mf][nf][r]);
        else
          ((float*)Cout)[(size_t)(row0 + r) * N + col] = acc[mf][nf][r];
      }
    }
  }
}

// ---------------- RoPE + scatter ----------------
__global__ __launch_bounds__(256) void rope_scatter_kernel(
    const unsigned short* __restrict__ qkv,
    unsigned short* __restrict__ Qo, unsigned short* __restrict__ Ko,
    unsigned short* __restrict__ Vt) {
  __shared__ unsigned short lV[32 * 128];
  const int bh = blockIdx.x;
  const int l0 = blockIdx.y * 32;
  const int b = bh >> 4, h = bh & 15;
  const int tid = threadIdx.x;
#pragma unroll
  for (int it = 0; it < 2; ++it) {
    int idx = it * 256 + tid;
    int ll = idx >> 4;
    int dq = idx & 15;
    int l = l0 + ll;
    const unsigned short* row = qkv + (size_t)(b * LSEQ + l) * NQKV + h * HD;
    bfx4 qlo = *(const bfx4*)(row + dq * 4);
    bfx4 qhi = *(const bfx4*)(row + 64 + dq * 4);
    bfx4 klo = *(const bfx4*)(row + 2048 + dq * 4);
    bfx4 khi = *(const bfx4*)(row + 2048 + 64 + dq * 4);
    bfx4 vlo = *(const bfx4*)(row + 4096 + dq * 4);
    bfx4 vhi = *(const bfx4*)(row + 4096 + 64 + dq * 4);
    bfx4 oqlo, oqhi, oklo, okhi;
#pragma unroll
    for (int e = 0; e < 4; ++e) {
      int d2 = dq * 4 + e;
      float invf = exp2f(-(float)d2 * 0.2076205059304601f);
      float fr = (float)l * invf;
      float s, c;
      sincosf(fr, &s, &c);
      float xq1 = bf2f((unsigned short)qlo[e]), xq2 = bf2f((unsigned short)qhi[e]);
      oqlo[e] = (short)f2bf(xq1 * c - xq2 * s);
      oqhi[e] = (short)f2bf(xq2 * c + xq1 * s);
      float xk1 = bf2f((unsigned short)klo[e]), xk2 = bf2f((unsigned short)khi[e]);
      oklo[e] = (short)f2bf(xk1 * c - xk2 * s);
      okhi[e] = (short)f2bf(xk2 * c + xk1 * s);
    }
    size_t obase = ((size_t)bh * LSEQ + l) * HD;
    *(bfx4*)(Qo + obase + dq * 4) = oqlo;
    *(bfx4*)(Qo + obase + 64 + dq * 4) = oqhi;
    *(bfx4*)(Ko + obase + dq * 4) = oklo;
    *(bfx4*)(Ko + obase + 64 + dq * 4) = okhi;
    *(bfx4*)(lV + ll * 128 + dq * 4) = vlo;
    *(bfx4*)(lV + ll * 128 + 64 + dq * 4) = vhi;
  }
  __syncthreads();
#pragma unroll
  for (int it = 0; it < 16; ++it) {
    int idx = it * 256 + tid;
    int d = idx >> 5;
    int ll = idx & 31;
    Vt[((size_t)bh * HD + d) * LSEQ + l0 + ll] = lV[ll * 128 + d];
  }
}

// ---------------- Flash attention: 8 waves, q-tile 128, KV chunk 64, LDS-staged ----------------
__global__ __launch_bounds__(512, 4) void flash_kernel(
    const unsigned short* __restrict__ Q, const unsigned short* __restrict__ K,
    const unsigned short* __restrict__ Vt, unsigned short* __restrict__ O) {
  __shared__ unsigned short lKs[2][64 * 128];
  __shared__ unsigned short lVs[2][128 * 64];
  __shared__ unsigned short lP[8][16 * 40];
  const int bh = blockIdx.x;
  const int qt = 15 - (int)blockIdx.y;
  const int q0 = qt * 128;
  const int tid = threadIdx.x;
  const int w = tid >> 6, lane = tid & 63;
  const int g = lane >> 4, ln = lane & 15;
  const int q0w = q0 + w * 16;
  const unsigned short* Qb = Q + (size_t)bh * LSEQ * HD;
  const unsigned short* Kb = K + (size_t)bh * LSEQ * HD;
  const unsigned short* Vb = Vt + (size_t)bh * HD * LSEQ;
  unsigned short* Pw = lP[w];

  auto STAGE = [&](int buf, int kv0s) {
#pragma unroll
    for (int s = 0; s < 2; ++s) {
      int rl = s * 32 + w * 4 + (lane >> 4);
      int slot = lane & 15;
      const unsigned short* src =
          Kb + (size_t)(kv0s + rl) * HD + ((slot ^ (rl & 15)) * 8);
      gload_lds16(src, &lKs[buf][(s * 8192 + w * 1024) / 2]);
    }
#pragma unroll
    for (int s = 0; s < 2; ++s) {
      int d = s * 64 + w * 8 + (lane >> 3);
      int slot = lane & 7;
      const unsigned short* src =
          Vb + (size_t)d * LSEQ + kv0s + ((slot ^ (d & 7)) * 8);
      gload_lds16(src, &lVs[buf][(s * 8192 + w * 1024) / 2]);
    }
  };

  bfx8 qf[4];
#pragma unroll
  for (int c = 0; c < 4; ++c)
    qf[c] = *(const bfx8*)(Qb + (size_t)(q0w + ln) * HD + c * 32 + g * 8);

  f32x4 o[8];
#pragma unroll
  for (int dt = 0; dt < 8; ++dt) o[dt] = (f32x4){0.f, 0.f, 0.f, 0.f};
  float m = -1e30f, sum = 0.f;
  const int qg = q0w + ln;
  const int nch = 2 * qt + 2;

  STAGE(0, 0);
  __syncthreads();

  for (int ch = 0; ch < nch; ++ch) {
    const int kv0 = ch * 64;
    const int cur = ch & 1;
    if (ch + 1 < nch) STAGE(cur ^ 1, kv0 + 64);

    if (kv0 <= q0w + 15) {
      const char* lK0 = (const char*)lKs[cur];
      const char* lV0 = (const char*)lVs[cur];
      f32x4 s4[4];
#pragma unroll
      for (int kt = 0; kt < 4; ++kt) s4[kt] = (f32x4){0.f, 0.f, 0.f, 0.f};
#pragma unroll
      for (int c = 0; c < 4; ++c) {
        const int cbb = c * 64 + g * 16;
#pragma unroll
        for (int kt = 0; kt < 4; ++kt) {
          bfx8 kf = *(const bfx8*)(lK0 + (kt * 16 + ln) * 256 + (cbb ^ (ln << 4)));
          s4[kt] = __builtin_amdgcn_mfma_f32_16x16x32_bf16(kf, qf[c], s4[kt], 0, 0, 0);
        }
      }
      float tm = -1e30f;
      if (kv0 + 63 <= q0w) {
#pragma unroll
        for (int kt = 0; kt < 4; ++kt)
#pragma unroll
          for (int r = 0; r < 4; ++r) {
            s4[kt][r] *= SCALE;
            tm = fmaxf(tm, s4[kt][r]);
          }
      } else {
#pragma unroll
        for (int kt = 0; kt < 4; ++kt)
#pragma unroll
          for (int r = 0; r < 4; ++r) {
            int kvr = kv0 + kt * 16 + 4 * g + r;
            float v = (kvr <= qg) ? s4[kt][r] * SCALE : -1e30f;
            s4[kt][r] = v;
            tm = fmaxf(tm, v);
          }
      }
      tm = fmaxf(tm, __shfl_xor(tm, 16));
      tm = fmaxf(tm, __shfl_xor(tm, 32));
      float f = 1.f;
      const bool dorescale = !__all(tm <= m + 8.f);
      if (dorescale) {
        float mnew = fmaxf(m, tm);
        f = __expf(m - mnew);
        m = mnew;
      }
      float ts = 0.f;
      bfx4 pb4[4];
#pragma unroll
      for (int kt = 0; kt < 4; ++kt)
#pragma unroll
        for (int r = 0; r < 4; ++r) {
          float p = __expf(s4[kt][r] - m);
          ts += p;
          pb4[kt][r] = (short)f2bf(p);
        }
      ts += __shfl_xor(ts, 16);
      ts += __shfl_xor(ts, 32);
      sum = sum * f + ts;
      float fr0 = 1.f, fr1 = 1.f, fr2 = 1.f, fr3 = 1.f;
      if (dorescale) {
        fr0 = __shfl(f, 4 * g + 0);
        fr1 = __shfl(f, 4 * g + 1);
        fr2 = __shfl(f, 4 * g + 2);
        fr3 = __shfl(f, 4 * g + 3);
      }
#pragma unroll
      for (int kvh = 0; kvh < 2; ++kvh) {
        asm volatile("s_waitcnt lgkmcnt(0)" ::: "memory");
        __builtin_amdgcn_sched_barrier(0);
        *(bfx4*)(Pw + ln * 40 + 4 * g) = pb4[2 * kvh];
        *(bfx4*)(Pw + ln * 40 + 16 + 4 * g) = pb4[2 * kvh + 1];
        asm volatile("s_waitcnt lgkmcnt(0)" ::: "memory");
        __builtin_amdgcn_sched_barrier(0);
        bfx8 pf = *(const bfx8*)(Pw + ln * 40 + g * 8);
        if (kvh == 0 && dorescale) {
#pragma unroll
          for (int dt = 0; dt < 8; ++dt) {
            o[dt][0] *= fr0; o[dt][1] *= fr1; o[dt][2] *= fr2; o[dt][3] *= fr3;
          }
        }
#pragma unroll
        for (int dt = 0; dt < 8; ++dt) {
          bfx8 vf = *(const bfx8*)(lV0 + (dt * 16 + ln) * 128 +
                                   ((kvh * 64 + g * 16) ^ ((ln & 7) << 4)));
          o[dt] = __builtin_amdgcn_mfma_f32_16x16x32_bf16(pf, vf, o[dt], 0, 0, 0);
        }
      }
    }
    __syncthreads();
  }

  float inv = 1.f / sum;
  float ir0 = __shfl(inv, 4 * g + 0);
  float ir1 = __shfl(inv, 4 * g + 1);
  float ir2 = __shfl(inv, 4 * g + 2);
  float ir3 = __shfl(inv, 4 * g + 3);
  const int b = bh >> 4, h = bh & 15;
  unsigned short* Ob = O + (size_t)b * LSEQ * HDIM + h * HD;
#pragma unroll
  for (int dt = 0; dt < 8; ++dt) {
    Ob[(size_t)(q0w + 4 * g + 0) * HDIM + dt * 16 + ln] = f2bf(o[dt][0] * ir0);
    Ob[(size_t)(q0w + 4 * g + 1) * HDIM + dt * 16 + ln] = f2bf(o[dt][1] * ir1);
    Ob[(size_t)(q0w + 4 * g + 2) * HDIM + dt * 16 + ln] = f2bf(o[dt][2] * ir2);
    Ob[(size_t)(q0w + 4 * g + 3) * HDIM + dt * 16 + ln] = f2bf(o[dt][3] * ir3);
  }
}

// ---------------- launch ----------------
extern "C" void kernel_launch(void* const* d_in, const int* in_sizes, int n_in,
                              void* d_out, int out_size, void* d_ws, size_t ws_size,
                              hipStream_t stream) {
  const float* x = (const float*)d_in[0];
  const float* w_qkv = (const float*)d_in[1];
  const float* w_o = (const float*)d_in[2];
  float* out = (float*)d_out;
  char* ws = (char*)d_ws;

  unsigned short* xb    = (unsigned short*)(ws + 0);
  unsigned short* wqkvb = (unsigned short*)(ws + 16777216);
  unsigned short* wob   = (unsigned short*)(ws + 41943040);
  unsigned short* qkvb  = (unsigned short*)(ws + 50331648);
  unsigned short* qb    = (unsigned short*)(ws + 100663296);
  unsigned short* kb    = (unsigned short*)(ws + 117440512);
  unsigned short* vtb   = (unsigned short*)(ws + 134217728);
  unsigned short* attnb = (unsigned short*)(ws + 0);

  cast_bf16_kernel<<<8388608 / 4 / 256, 256, 0, stream>>>(x, xb, 8388608 / 4);
  cast_bf16_kernel<<<12582912 / 4 / 256, 256, 0, stream>>>(w_qkv, wqkvb, 12582912 / 4);
  cast_bf16_kernel<<<4194304 / 4 / 256, 256, 0, stream>>>(w_o, wob, 4194304 / 4);

  // QKV: 256x192 tiles -> 16*32 = 512 blocks = 2 rounds
  gemm_hyb_kernel<6, true><<<(4096 / 256) * (6144 / 192), 512, 0, stream>>>(
      xb, wqkvb, (void*)qkvb, 4096, 6144, 2048);

  rope_scatter_kernel<<<dim3(32, 64), 256, 0, stream>>>(qkvb, qb, kb, vtb);

  flash_kernel<<<dim3(32, 16), 512, 0, stream>>>(qb, kb, vtb, attnb);

  // out-proj: 256x128 tiles -> 16*16 = 256 blocks = 1 round
  gemm_hyb_kernel<4, false><<<(4096 / 256) * (2048 / 128), 512, 0, stream>>>(
      attnb, wob, (void*)out, 4096, 2048, 2048);
}

// Round 11
// 267.140 us; speedup vs baseline: 2.0921x; 1.6294x over previous
//
#include <hip/hip_runtime.h>

#define NHEADS 16
#define HD 128
#define LSEQ 2048
#define NBATCH 2
#define HDIM 2048
#define NQKV 6144
#define SCALE 0.08838834764831845f

typedef __attribute__((ext_vector_type(8))) short bfx8;
typedef __attribute__((ext_vector_type(4))) short bfx4;
typedef __attribute__((ext_vector_type(4))) float f32x4;

__device__ __forceinline__ unsigned short f2bf(float x) {
  unsigned u = __float_as_uint(x);
  u += 0x7fffu + ((u >> 16) & 1u);
  return (unsigned short)(u >> 16);
}
__device__ __forceinline__ float bf2f(unsigned short u) {
  return __uint_as_float(((unsigned)u) << 16);
}
__device__ __forceinline__ void gload_lds16(const void* g, void* l) {
  __builtin_amdgcn_global_load_lds(
      (const __attribute__((address_space(1))) unsigned int*)g,
      (__attribute__((address_space(3))) unsigned int*)l, 16, 0, 0);
}

// ---------------- cast f32 -> bf16 (vectorized) ----------------
__global__ __launch_bounds__(256) void cast_bf16_kernel(
    const float* __restrict__ in, unsigned short* __restrict__ out, int n4) {
  int i = blockIdx.x * 256 + threadIdx.x;
  if (i >= n4) return;
  float4 v = ((const float4*)in)[i];
  bfx4 o;
  o[0] = (short)f2bf(v.x);
  o[1] = (short)f2bf(v.y);
  o[2] = (short)f2bf(v.z);
  o[3] = (short)f2bf(v.w);
  ((bfx4*)out)[i] = o;
}

// ---------------- GEMM 128 x BN, BK=64, 8 waves, barrier-light, 2 blocks/CU ----------------
// C[M,N] = A[M,K] * B[N,K]^T. R7's loop (stage next tile -> compiler-scheduled
// ds_reads+MFMA -> one vmcnt(0)+barrier), resized so TWO independent blocks
// co-reside per CU (LDS 80/64 KB): block X's tile-boundary drain overlaps
// block Y's MFMA stream without any pinned schedule.
template<int BN, bool BF16OUT>
__global__ __launch_bounds__(512, 4) void gemm128_kernel(
    const unsigned short* __restrict__ A, const unsigned short* __restrict__ B,
    void* __restrict__ Cout, int M, int N, int K) {
  constexpr int NF = BN / 64;             // per-wave N fragments (BN/4/16)
  constexpr int AQ = 2, BQ = BN / 64;     // stage instructions per matrix
  __shared__ unsigned short lA[2][128 * 64];
  __shared__ unsigned short lB[2][BN * 64];
  const int tid = threadIdx.x;
  const int w = tid >> 6, lane = tid & 63;
  const int g = lane >> 4, ln = lane & 15;
  const int nmt = M >> 7, nnt = N / BN;
  const int nwg = nmt * nnt;
  const int bid = blockIdx.x;
  const int swz = (bid & 7) * (nwg >> 3) + (bid >> 3);  // nwg % 8 == 0
  const int bm = (swz / nnt) * 128, bn = (swz % nnt) * BN;
  const int wm = (w >> 2) * 64;           // 2 M-splits
  const int wn = (w & 3) * (NF * 16);     // 4 N-splits
  const unsigned short* At = A + (size_t)bm * K;
  const unsigned short* Bt = B + (size_t)bn * K;

  // stage one 64-row slab (16B/lane, wave-linear LDS dst, pre-swizzled src)
  auto STG = [&](const unsigned short* src, unsigned short* dst, int q, int k0) {
    int rid = q * 64 + w * 8 + (lane >> 3);
    int slot = lane & 7;
    gload_lds16(src + (size_t)rid * K + k0 + ((slot ^ (rid & 7)) << 3),
                dst + (size_t)(q * 4096 + w * 512));
  };
  auto STAGE_ALL = [&](int buf, int k0) {
#pragma unroll
    for (int q = 0; q < BQ; ++q) STG(Bt, lB[buf], q, k0);
#pragma unroll
    for (int q = 0; q < AQ; ++q) STG(At, lA[buf], q, k0);
  };

  f32x4 acc[4][NF];
#pragma unroll
  for (int i = 0; i < 4; ++i)
#pragma unroll
    for (int j = 0; j < NF; ++j) acc[i][j] = (f32x4){0.f, 0.f, 0.f, 0.f};

  STAGE_ALL(0, 0);
  asm volatile("s_waitcnt vmcnt(0)" ::: "memory");
  __builtin_amdgcn_s_barrier();

  const int nt = K >> 6;
  for (int t = 0; t < nt; ++t) {
    const int cur = t & 1;
    const char* lAc = (const char*)lA[cur];
    const char* lBc = (const char*)lB[cur];
    const bool more = (t + 1 < nt);
    if (more) STAGE_ALL(cur ^ 1, (t + 1) << 6);

    bfx8 bfrag[NF][2];
#pragma unroll
    for (int nf = 0; nf < NF; ++nf)
#pragma unroll
      for (int kk = 0; kk < 2; ++kk)
        bfrag[nf][kk] = *(const bfx8*)(lBc + (wn + nf * 16 + ln) * 128 +
                                       (((kk * 4 + g) ^ (ln & 7)) << 4));
#pragma unroll
    for (int mf = 0; mf < 4; ++mf) {
      bfx8 afrag[2];
#pragma unroll
      for (int kk = 0; kk < 2; ++kk)
        afrag[kk] = *(const bfx8*)(lAc + (wm + mf * 16 + ln) * 128 +
                                   (((kk * 4 + g) ^ (ln & 7)) << 4));
#pragma unroll
      for (int kk = 0; kk < 2; ++kk)
#pragma unroll
        for (int nf = 0; nf < NF; ++nf)
          acc[mf][nf] = __builtin_amdgcn_mfma_f32_16x16x32_bf16(
              afrag[kk], bfrag[nf][kk], acc[mf][nf], 0, 0, 0);
    }

    asm volatile("s_waitcnt vmcnt(0)" ::: "memory");
    __builtin_amdgcn_s_barrier();
  }

#pragma unroll
  for (int mf = 0; mf < 4; ++mf) {
    int row0 = bm + wm + mf * 16 + g * 4;
#pragma unroll
    for (int nf = 0; nf < NF; ++nf) {
      int col = bn + wn + nf * 16 + ln;
#pragma unroll
      for (int r = 0; r < 4; ++r) {
        if constexpr (BF16OUT)
          ((unsigned short*)Cout)[(size_t)(row0 + r) * N + col] = f2bf(acc[mf][nf][r]);
        else
          ((float*)Cout)[(size_t)(row0 + r) * N + col] = acc[mf][nf][r];
      }
    }
  }
}

// ---------------- RoPE + scatter ----------------
__global__ __launch_bounds__(256) void rope_scatter_kernel(
    const unsigned short* __restrict__ qkv,
    unsigned short* __restrict__ Qo, unsigned short* __restrict__ Ko,
    unsigned short* __restrict__ Vt) {
  __shared__ unsigned short lV[32 * 128];
  const int bh = blockIdx.x;
  const int l0 = blockIdx.y * 32;
  const int b = bh >> 4, h = bh & 15;
  const int tid = threadIdx.x;
#pragma unroll
  for (int it = 0; it < 2; ++it) {
    int idx = it * 256 + tid;
    int ll = idx >> 4;
    int dq = idx & 15;
    int l = l0 + ll;
    const unsigned short* row = qkv + (size_t)(b * LSEQ + l) * NQKV + h * HD;
    bfx4 qlo = *(const bfx4*)(row + dq * 4);
    bfx4 qhi = *(const bfx4*)(row + 64 + dq * 4);
    bfx4 klo = *(const bfx4*)(row + 2048 + dq * 4);
    bfx4 khi = *(const bfx4*)(row + 2048 + 64 + dq * 4);
    bfx4 vlo = *(const bfx4*)(row + 4096 + dq * 4);
    bfx4 vhi = *(const bfx4*)(row + 4096 + 64 + dq * 4);
    bfx4 oqlo, oqhi, oklo, okhi;
#pragma unroll
    for (int e = 0; e < 4; ++e) {
      int d2 = dq * 4 + e;
      float invf = exp2f(-(float)d2 * 0.2076205059304601f);
      float fr = (float)l * invf;
      float s, c;
      sincosf(fr, &s, &c);
      float xq1 = bf2f((unsigned short)qlo[e]), xq2 = bf2f((unsigned short)qhi[e]);
      oqlo[e] = (short)f2bf(xq1 * c - xq2 * s);
      oqhi[e] = (short)f2bf(xq2 * c + xq1 * s);
      float xk1 = bf2f((unsigned short)klo[e]), xk2 = bf2f((unsigned short)khi[e]);
      oklo[e] = (short)f2bf(xk1 * c - xk2 * s);
      okhi[e] = (short)f2bf(xk2 * c + xk1 * s);
    }
    size_t obase = ((size_t)bh * LSEQ + l) * HD;
    *(bfx4*)(Qo + obase + dq * 4) = oqlo;
    *(bfx4*)(Qo + obase + 64 + dq * 4) = oqhi;
    *(bfx4*)(Ko + obase + dq * 4) = oklo;
    *(bfx4*)(Ko + obase + 64 + dq * 4) = okhi;
    *(bfx4*)(lV + ll * 128 + dq * 4) = vlo;
    *(bfx4*)(lV + ll * 128 + 64 + dq * 4) = vhi;
  }
  __syncthreads();
#pragma unroll
  for (int it = 0; it < 16; ++it) {
    int idx = it * 256 + tid;
    int d = idx >> 5;
    int ll = idx & 31;
    Vt[((size_t)bh * HD + d) * LSEQ + l0 + ll] = lV[ll * 128 + d];
  }
}

// ---------------- Flash attention: 8 waves, q-tile 128, KV chunk 64, LDS-staged ----------------
__global__ __launch_bounds__(512, 4) void flash_kernel(
    const unsigned short* __restrict__ Q, const unsigned short* __restrict__ K,
    const unsigned short* __restrict__ Vt, unsigned short* __restrict__ O) {
  __shared__ unsigned short lKs[2][64 * 128];
  __shared__ unsigned short lVs[2][128 * 64];
  __shared__ unsigned short lP[8][16 * 40];
  const int bh = blockIdx.x;
  const int qt = 15 - (int)blockIdx.y;
  const int q0 = qt * 128;
  const int tid = threadIdx.x;
  const int w = tid >> 6, lane = tid & 63;
  const int g = lane >> 4, ln = lane & 15;
  const int q0w = q0 + w * 16;
  const unsigned short* Qb = Q + (size_t)bh * LSEQ * HD;
  const unsigned short* Kb = K + (size_t)bh * LSEQ * HD;
  const unsigned short* Vb = Vt + (size_t)bh * HD * LSEQ;
  unsigned short* Pw = lP[w];

  auto STAGE = [&](int buf, int kv0s) {
#pragma unroll
    for (int s = 0; s < 2; ++s) {
      int rl = s * 32 + w * 4 + (lane >> 4);
      int slot = lane & 15;
      const unsigned short* src =
          Kb + (size_t)(kv0s + rl) * HD + ((slot ^ (rl & 15)) * 8);
      gload_lds16(src, &lKs[buf][(s * 8192 + w * 1024) / 2]);
    }
#pragma unroll
    for (int s = 0; s < 2; ++s) {
      int d = s * 64 + w * 8 + (lane >> 3);
      int slot = lane & 7;
      const unsigned short* src =
          Vb + (size_t)d * LSEQ + kv0s + ((slot ^ (d & 7)) * 8);
      gload_lds16(src, &lVs[buf][(s * 8192 + w * 1024) / 2]);
    }
  };

  bfx8 qf[4];
#pragma unroll
  for (int c = 0; c < 4; ++c)
    qf[c] = *(const bfx8*)(Qb + (size_t)(q0w + ln) * HD + c * 32 + g * 8);

  f32x4 o[8];
#pragma unroll
  for (int dt = 0; dt < 8; ++dt) o[dt] = (f32x4){0.f, 0.f, 0.f, 0.f};
  float m = -1e30f, sum = 0.f;
  const int qg = q0w + ln;
  const int nch = 2 * qt + 2;

  STAGE(0, 0);
  __syncthreads();

  for (int ch = 0; ch < nch; ++ch) {
    const int kv0 = ch * 64;
    const int cur = ch & 1;
    if (ch + 1 < nch) STAGE(cur ^ 1, kv0 + 64);

    if (kv0 <= q0w + 15) {
      const char* lK0 = (const char*)lKs[cur];
      const char* lV0 = (const char*)lVs[cur];
      f32x4 s4[4];
#pragma unroll
      for (int kt = 0; kt < 4; ++kt) s4[kt] = (f32x4){0.f, 0.f, 0.f, 0.f};
#pragma unroll
      for (int c = 0; c < 4; ++c) {
        const int cbb = c * 64 + g * 16;
#pragma unroll
        for (int kt = 0; kt < 4; ++kt) {
          bfx8 kf = *(const bfx8*)(lK0 + (kt * 16 + ln) * 256 + (cbb ^ (ln << 4)));
          s4[kt] = __builtin_amdgcn_mfma_f32_16x16x32_bf16(kf, qf[c], s4[kt], 0, 0, 0);
        }
      }
      float tm = -1e30f;
      if (kv0 + 63 <= q0w) {
#pragma unroll
        for (int kt = 0; kt < 4; ++kt)
#pragma unroll
          for (int r = 0; r < 4; ++r) {
            s4[kt][r] *= SCALE;
            tm = fmaxf(tm, s4[kt][r]);
          }
      } else {
#pragma unroll
        for (int kt = 0; kt < 4; ++kt)
#pragma unroll
          for (int r = 0; r < 4; ++r) {
            int kvr = kv0 + kt * 16 + 4 * g + r;
            float v = (kvr <= qg) ? s4[kt][r] * SCALE : -1e30f;
            s4[kt][r] = v;
            tm = fmaxf(tm, v);
          }
      }
      tm = fmaxf(tm, __shfl_xor(tm, 16));
      tm = fmaxf(tm, __shfl_xor(tm, 32));
      float f = 1.f;
      const bool dorescale = !__all(tm <= m + 8.f);
      if (dorescale) {
        float mnew = fmaxf(m, tm);
        f = __expf(m - mnew);
        m = mnew;
      }
      float ts = 0.f;
      bfx4 pb4[4];
#pragma unroll
      for (int kt = 0; kt < 4; ++kt)
#pragma unroll
        for (int r = 0; r < 4; ++r) {
          float p = __expf(s4[kt][r] - m);
          ts += p;
          pb4[kt][r] = (short)f2bf(p);
        }
      ts += __shfl_xor(ts, 16);
      ts += __shfl_xor(ts, 32);
      sum = sum * f + ts;
      float fr0 = 1.f, fr1 = 1.f, fr2 = 1.f, fr3 = 1.f;
      if (dorescale) {
        fr0 = __shfl(f, 4 * g + 0);
        fr1 = __shfl(f, 4 * g + 1);
        fr2 = __shfl(f, 4 * g + 2);
        fr3 = __shfl(f, 4 * g + 3);
      }
#pragma unroll
      for (int kvh = 0; kvh < 2; ++kvh) {
        asm volatile("s_waitcnt lgkmcnt(0)" ::: "memory");
        __builtin_amdgcn_sched_barrier(0);
        *(bfx4*)(Pw + ln * 40 + 4 * g) = pb4[2 * kvh];
        *(bfx4*)(Pw + ln * 40 + 16 + 4 * g) = pb4[2 * kvh + 1];
        asm volatile("s_waitcnt lgkmcnt(0)" ::: "memory");
        __builtin_amdgcn_sched_barrier(0);
        bfx8 pf = *(const bfx8*)(Pw + ln * 40 + g * 8);
        if (kvh == 0 && dorescale) {
#pragma unroll
          for (int dt = 0; dt < 8; ++dt) {
            o[dt][0] *= fr0; o[dt][1] *= fr1; o[dt][2] *= fr2; o[dt][3] *= fr3;
          }
        }
#pragma unroll
        for (int dt = 0; dt < 8; ++dt) {
          bfx8 vf = *(const bfx8*)(lV0 + (dt * 16 + ln) * 128 +
                                   ((kvh * 64 + g * 16) ^ ((ln & 7) << 4)));
          o[dt] = __builtin_amdgcn_mfma_f32_16x16x32_bf16(pf, vf, o[dt], 0, 0, 0);
        }
      }
    }
    __syncthreads();
  }

  float inv = 1.f / sum;
  float ir0 = __shfl(inv, 4 * g + 0);
  float ir1 = __shfl(inv, 4 * g + 1);
  float ir2 = __shfl(inv, 4 * g + 2);
  float ir3 = __shfl(inv, 4 * g + 3);
  const int b = bh >> 4, h = bh & 15;
  unsigned short* Ob = O + (size_t)b * LSEQ * HDIM + h * HD;
#pragma unroll
  for (int dt = 0; dt < 8; ++dt) {
    Ob[(size_t)(q0w + 4 * g + 0) * HDIM + dt * 16 + ln] = f2bf(o[dt][0] * ir0);
    Ob[(size_t)(q0w + 4 * g + 1) * HDIM + dt * 16 + ln] = f2bf(o[dt][1] * ir1);
    Ob[(size_t)(q0w + 4 * g + 2) * HDIM + dt * 16 + ln] = f2bf(o[dt][2] * ir2);
    Ob[(size_t)(q0w + 4 * g + 3) * HDIM + dt * 16 + ln] = f2bf(o[dt][3] * ir3);
  }
}

// ---------------- launch ----------------
extern "C" void kernel_launch(void* const* d_in, const int* in_sizes, int n_in,
                              void* d_out, int out_size, void* d_ws, size_t ws_size,
                              hipStream_t stream) {
  const float* x = (const float*)d_in[0];
  const float* w_qkv = (const float*)d_in[1];
  const float* w_o = (const float*)d_in[2];
  float* out = (float*)d_out;
  char* ws = (char*)d_ws;

  unsigned short* xb    = (unsigned short*)(ws + 0);
  unsigned short* wqkvb = (unsigned short*)(ws + 16777216);
  unsigned short* wob   = (unsigned short*)(ws + 41943040);
  unsigned short* qkvb  = (unsigned short*)(ws + 50331648);
  unsigned short* qb    = (unsigned short*)(ws + 100663296);
  unsigned short* kb    = (unsigned short*)(ws + 117440512);
  unsigned short* vtb   = (unsigned short*)(ws + 134217728);
  unsigned short* attnb = (unsigned short*)(ws + 0);

  cast_bf16_kernel<<<8388608 / 4 / 256, 256, 0, stream>>>(x, xb, 8388608 / 4);
  cast_bf16_kernel<<<12582912 / 4 / 256, 256, 0, stream>>>(w_qkv, wqkvb, 12582912 / 4);
  cast_bf16_kernel<<<4194304 / 4 / 256, 256, 0, stream>>>(w_o, wob, 4194304 / 4);

  // QKV: 128x192 tiles -> 32*32 = 1024 blocks = 2 rounds at 2 blocks/CU
  gemm128_kernel<192, true><<<(4096 / 128) * (6144 / 192), 512, 0, stream>>>(
      xb, wqkvb, (void*)qkvb, 4096, 6144, 2048);

  rope_scatter_kernel<<<dim3(32, 64), 256, 0, stream>>>(qkvb, qb, kb, vtb);

  flash_kernel<<<dim3(32, 16), 512, 0, stream>>>(qb, kb, vtb, attnb);

  // out-proj: 128x128 tiles -> 32*16 = 512 blocks = 1 round at 2 blocks/CU
  gemm128_kernel<128, false><<<(4096 / 128) * (2048 / 128), 512, 0, stream>>>(
      attnb, wob, (void*)out, 4096, 2048, 2048);
}

// Round 12
// 261.060 us; speedup vs baseline: 2.1408x; 1.0233x over previous
//
#include <hip/hip_runtime.h>

#define NHEADS 16
#define HD 128
#define LSEQ 2048
#define NBATCH 2
#define HDIM 2048
#define NQKV 6144
#define SCALE 0.08838834764831845f

typedef __attribute__((ext_vector_type(8))) short bfx8;
typedef __attribute__((ext_vector_type(4))) short bfx4;
typedef __attribute__((ext_vector_type(4))) float f32x4;

__device__ __forceinline__ unsigned short f2bf(float x) {
  unsigned u = __float_as_uint(x);
  u += 0x7fffu + ((u >> 16) & 1u);
  return (unsigned short)(u >> 16);
}
__device__ __forceinline__ float bf2f(unsigned short u) {
  return __uint_as_float(((unsigned)u) << 16);
}
__device__ __forceinline__ void gload_lds16(const void* g, void* l) {
  __builtin_amdgcn_global_load_lds(
      (const __attribute__((address_space(1))) unsigned int*)g,
      (__attribute__((address_space(3))) unsigned int*)l, 16, 0, 0);
}

// ---------------- fused cast f32 -> bf16 for x, w_qkv, w_o ----------------
// Segment boundaries are multiples of 256 float4s -> block-uniform branches.
__global__ __launch_bounds__(256) void cast_all_kernel(
    const float* __restrict__ x, const float* __restrict__ wq,
    const float* __restrict__ wo, unsigned short* __restrict__ xb,
    unsigned short* __restrict__ wqb, unsigned short* __restrict__ wob) {
  int i = blockIdx.x * 256 + threadIdx.x;
  const float* in;
  unsigned short* out;
  int li;
  if (i < 2097152) { in = x; out = xb; li = i; }
  else if (i < 2097152 + 3145728) { in = wq; out = wqb; li = i - 2097152; }
  else { in = wo; out = wob; li = i - (2097152 + 3145728); }
  float4 v = ((const float4*)in)[li];
  bfx4 o;
  o[0] = (short)f2bf(v.x);
  o[1] = (short)f2bf(v.y);
  o[2] = (short)f2bf(v.z);
  o[3] = (short)f2bf(v.w);
  ((bfx4*)out)[li] = o;
}

// ---------------- GEMM 128 x BN, BK=64, 8 waves, barrier-light, 2 blocks/CU ----------------
template<int BN, bool BF16OUT>
__global__ __launch_bounds__(512, 4) void gemm128_kernel(
    const unsigned short* __restrict__ A, const unsigned short* __restrict__ B,
    void* __restrict__ Cout, int M, int N, int K) {
  constexpr int NF = BN / 64;
  constexpr int AQ = 2, BQ = BN / 64;
  __shared__ unsigned short lA[2][128 * 64];
  __shared__ unsigned short lB[2][BN * 64];
  const int tid = threadIdx.x;
  const int w = tid >> 6, lane = tid & 63;
  const int g = lane >> 4, ln = lane & 15;
  const int nmt = M >> 7, nnt = N / BN;
  const int nwg = nmt * nnt;
  const int bid = blockIdx.x;
  const int swz = (bid & 7) * (nwg >> 3) + (bid >> 3);  // nwg % 8 == 0
  const int bm = (swz / nnt) * 128, bn = (swz % nnt) * BN;
  const int wm = (w >> 2) * 64;
  const int wn = (w & 3) * (NF * 16);
  const unsigned short* At = A + (size_t)bm * K;
  const unsigned short* Bt = B + (size_t)bn * K;

  auto STG = [&](const unsigned short* src, unsigned short* dst, int q, int k0) {
    int rid = q * 64 + w * 8 + (lane >> 3);
    int slot = lane & 7;
    gload_lds16(src + (size_t)rid * K + k0 + ((slot ^ (rid & 7)) << 3),
                dst + (size_t)(q * 4096 + w * 512));
  };
  auto STAGE_ALL = [&](int buf, int k0) {
#pragma unroll
    for (int q = 0; q < BQ; ++q) STG(Bt, lB[buf], q, k0);
#pragma unroll
    for (int q = 0; q < AQ; ++q) STG(At, lA[buf], q, k0);
  };

  f32x4 acc[4][NF];
#pragma unroll
  for (int i = 0; i < 4; ++i)
#pragma unroll
    for (int j = 0; j < NF; ++j) acc[i][j] = (f32x4){0.f, 0.f, 0.f, 0.f};

  STAGE_ALL(0, 0);
  asm volatile("s_waitcnt vmcnt(0)" ::: "memory");
  __builtin_amdgcn_s_barrier();

  const int nt = K >> 6;
  for (int t = 0; t < nt; ++t) {
    const int cur = t & 1;
    const char* lAc = (const char*)lA[cur];
    const char* lBc = (const char*)lB[cur];
    const bool more = (t + 1 < nt);
    if (more) STAGE_ALL(cur ^ 1, (t + 1) << 6);

    bfx8 bfrag[NF][2];
#pragma unroll
    for (int nf = 0; nf < NF; ++nf)
#pragma unroll
      for (int kk = 0; kk < 2; ++kk)
        bfrag[nf][kk] = *(const bfx8*)(lBc + (wn + nf * 16 + ln) * 128 +
                                       (((kk * 4 + g) ^ (ln & 7)) << 4));
#pragma unroll
    for (int mf = 0; mf < 4; ++mf) {
      bfx8 afrag[2];
#pragma unroll
      for (int kk = 0; kk < 2; ++kk)
        afrag[kk] = *(const bfx8*)(lAc + (wm + mf * 16 + ln) * 128 +
                                   (((kk * 4 + g) ^ (ln & 7)) << 4));
#pragma unroll
      for (int kk = 0; kk < 2; ++kk)
#pragma unroll
        for (int nf = 0; nf < NF; ++nf)
          acc[mf][nf] = __builtin_amdgcn_mfma_f32_16x16x32_bf16(
              afrag[kk], bfrag[nf][kk], acc[mf][nf], 0, 0, 0);
    }

    asm volatile("s_waitcnt vmcnt(0)" ::: "memory");
    __builtin_amdgcn_s_barrier();
  }

#pragma unroll
  for (int mf = 0; mf < 4; ++mf) {
    int row0 = bm + wm + mf * 16 + g * 4;
#pragma unroll
    for (int nf = 0; nf < NF; ++nf) {
      int col = bn + wn + nf * 16 + ln;
#pragma unroll
      for (int r = 0; r < 4; ++r) {
        if constexpr (BF16OUT)
          ((unsigned short*)Cout)[(size_t)(row0 + r) * N + col] = f2bf(acc[mf][nf][r]);
        else
          ((float*)Cout)[(size_t)(row0 + r) * N + col] = acc[mf][nf][r];
      }
    }
  }
}

// ---------------- RoPE + scatter ----------------
__global__ __launch_bounds__(256) void rope_scatter_kernel(
    const unsigned short* __restrict__ qkv,
    unsigned short* __restrict__ Qo, unsigned short* __restrict__ Ko,
    unsigned short* __restrict__ Vt) {
  __shared__ unsigned short lV[32 * 128];
  const int bh = blockIdx.x;
  const int l0 = blockIdx.y * 32;
  const int b = bh >> 4, h = bh & 15;
  const int tid = threadIdx.x;
#pragma unroll
  for (int it = 0; it < 2; ++it) {
    int idx = it * 256 + tid;
    int ll = idx >> 4;
    int dq = idx & 15;
    int l = l0 + ll;
    const unsigned short* row = qkv + (size_t)(b * LSEQ + l) * NQKV + h * HD;
    bfx4 qlo = *(const bfx4*)(row + dq * 4);
    bfx4 qhi = *(const bfx4*)(row + 64 + dq * 4);
    bfx4 klo = *(const bfx4*)(row + 2048 + dq * 4);
    bfx4 khi = *(const bfx4*)(row + 2048 + 64 + dq * 4);
    bfx4 vlo = *(const bfx4*)(row + 4096 + dq * 4);
    bfx4 vhi = *(const bfx4*)(row + 4096 + 64 + dq * 4);
    bfx4 oqlo, oqhi, oklo, okhi;
#pragma unroll
    for (int e = 0; e < 4; ++e) {
      int d2 = dq * 4 + e;
      float invf = exp2f(-(float)d2 * 0.2076205059304601f);
      float fr = (float)l * invf;
      float s, c;
      sincosf(fr, &s, &c);
      float xq1 = bf2f((unsigned short)qlo[e]), xq2 = bf2f((unsigned short)qhi[e]);
      oqlo[e] = (short)f2bf(xq1 * c - xq2 * s);
      oqhi[e] = (short)f2bf(xq2 * c + xq1 * s);
      float xk1 = bf2f((unsigned short)klo[e]), xk2 = bf2f((unsigned short)khi[e]);
      oklo[e] = (short)f2bf(xk1 * c - xk2 * s);
      okhi[e] = (short)f2bf(xk2 * c + xk1 * s);
    }
    size_t obase = ((size_t)bh * LSEQ + l) * HD;
    *(bfx4*)(Qo + obase + dq * 4) = oqlo;
    *(bfx4*)(Qo + obase + 64 + dq * 4) = oqhi;
    *(bfx4*)(Ko + obase + dq * 4) = oklo;
    *(bfx4*)(Ko + obase + 64 + dq * 4) = okhi;
    *(bfx4*)(lV + ll * 128 + dq * 4) = vlo;
    *(bfx4*)(lV + ll * 128 + 64 + dq * 4) = vhi;
  }
  __syncthreads();
#pragma unroll
  for (int it = 0; it < 16; ++it) {
    int idx = it * 256 + tid;
    int d = idx >> 5;
    int ll = idx & 31;
    Vt[((size_t)bh * HD + d) * LSEQ + l0 + ll] = lV[ll * 128 + d];
  }
}

// ---------------- Flash attention: 8 waves, q-tile 128, KV chunk 64, LDS-staged ----------------
// qt remap pairs heavy+light tiles onto the same CU (dispatch pairs block L with
// L+256 at 2 blocks/CU): qt = qy<8 ? 15-qy : qy-8 -> per-CU chunk-sum == 36.
__global__ __launch_bounds__(512, 4) void flash_kernel(
    const unsigned short* __restrict__ Q, const unsigned short* __restrict__ K,
    const unsigned short* __restrict__ Vt, unsigned short* __restrict__ O) {
  __shared__ unsigned short lKs[2][64 * 128];
  __shared__ unsigned short lVs[2][128 * 64];
  __shared__ unsigned short lP[8][16 * 40];
  const int bh = blockIdx.x;
  const int qy = (int)blockIdx.y;
  const int qt = (qy < 8) ? (15 - qy) : (qy - 8);
  const int q0 = qt * 128;
  const int tid = threadIdx.x;
  const int w = tid >> 6, lane = tid & 63;
  const int g = lane >> 4, ln = lane & 15;
  const int q0w = q0 + w * 16;
  const unsigned short* Qb = Q + (size_t)bh * LSEQ * HD;
  const unsigned short* Kb = K + (size_t)bh * LSEQ * HD;
  const unsigned short* Vb = Vt + (size_t)bh * HD * LSEQ;
  unsigned short* Pw = lP[w];

  auto STAGE = [&](int buf, int kv0s) {
#pragma unroll
    for (int s = 0; s < 2; ++s) {
      int rl = s * 32 + w * 4 + (lane >> 4);
      int slot = lane & 15;
      const unsigned short* src =
          Kb + (size_t)(kv0s + rl) * HD + ((slot ^ (rl & 15)) * 8);
      gload_lds16(src, &lKs[buf][(s * 8192 + w * 1024) / 2]);
    }
#pragma unroll
    for (int s = 0; s < 2; ++s) {
      int d = s * 64 + w * 8 + (lane >> 3);
      int slot = lane & 7;
      const unsigned short* src =
          Vb + (size_t)d * LSEQ + kv0s + ((slot ^ (d & 7)) * 8);
      gload_lds16(src, &lVs[buf][(s * 8192 + w * 1024) / 2]);
    }
  };

  bfx8 qf[4];
#pragma unroll
  for (int c = 0; c < 4; ++c)
    qf[c] = *(const bfx8*)(Qb + (size_t)(q0w + ln) * HD + c * 32 + g * 8);

  f32x4 o[8];
#pragma unroll
  for (int dt = 0; dt < 8; ++dt) o[dt] = (f32x4){0.f, 0.f, 0.f, 0.f};
  float m = -1e30f, sum = 0.f;
  const int qg = q0w + ln;
  const int nch = 2 * qt + 2;

  STAGE(0, 0);
  __syncthreads();

  for (int ch = 0; ch < nch; ++ch) {
    const int kv0 = ch * 64;
    const int cur = ch & 1;
    if (ch + 1 < nch) STAGE(cur ^ 1, kv0 + 64);

    if (kv0 <= q0w + 15) {
      const char* lK0 = (const char*)lKs[cur];
      const char* lV0 = (const char*)lVs[cur];
      f32x4 s4[4];
#pragma unroll
      for (int kt = 0; kt < 4; ++kt) s4[kt] = (f32x4){0.f, 0.f, 0.f, 0.f};
      __builtin_amdgcn_s_setprio(1);
#pragma unroll
      for (int c = 0; c < 4; ++c) {
        const int cbb = c * 64 + g * 16;
#pragma unroll
        for (int kt = 0; kt < 4; ++kt) {
          bfx8 kf = *(const bfx8*)(lK0 + (kt * 16 + ln) * 256 + (cbb ^ (ln << 4)));
          s4[kt] = __builtin_amdgcn_mfma_f32_16x16x32_bf16(kf, qf[c], s4[kt], 0, 0, 0);
        }
      }
      __builtin_amdgcn_s_setprio(0);
      float tm = -1e30f;
      if (kv0 + 63 <= q0w) {
#pragma unroll
        for (int kt = 0; kt < 4; ++kt)
#pragma unroll
          for (int r = 0; r < 4; ++r) {
            s4[kt][r] *= SCALE;
            tm = fmaxf(tm, s4[kt][r]);
          }
      } else {
#pragma unroll
        for (int kt = 0; kt < 4; ++kt)
#pragma unroll
          for (int r = 0; r < 4; ++r) {
            int kvr = kv0 + kt * 16 + 4 * g + r;
            float v = (kvr <= qg) ? s4[kt][r] * SCALE : -1e30f;
            s4[kt][r] = v;
            tm = fmaxf(tm, v);
          }
      }
      tm = fmaxf(tm, __shfl_xor(tm, 16));
      tm = fmaxf(tm, __shfl_xor(tm, 32));
      float f = 1.f;
      const bool dorescale = !__all(tm <= m + 8.f);
      if (dorescale) {
        float mnew = fmaxf(m, tm);
        f = __expf(m - mnew);
        m = mnew;
      }
      float ts = 0.f;
      bfx4 pb4[4];
#pragma unroll
      for (int kt = 0; kt < 4; ++kt)
#pragma unroll
        for (int r = 0; r < 4; ++r) {
          float p = __expf(s4[kt][r] - m);
          ts += p;
          pb4[kt][r] = (short)f2bf(p);
        }
      ts += __shfl_xor(ts, 16);
      ts += __shfl_xor(ts, 32);
      sum = sum * f + ts;
      float fr0 = 1.f, fr1 = 1.f, fr2 = 1.f, fr3 = 1.f;
      if (dorescale) {
        fr0 = __shfl(f, 4 * g + 0);
        fr1 = __shfl(f, 4 * g + 1);
        fr2 = __shfl(f, 4 * g + 2);
        fr3 = __shfl(f, 4 * g + 3);
      }
#pragma unroll
      for (int kvh = 0; kvh < 2; ++kvh) {
        asm volatile("s_waitcnt lgkmcnt(0)" ::: "memory");
        __builtin_amdgcn_sched_barrier(0);
        *(bfx4*)(Pw + ln * 40 + 4 * g) = pb4[2 * kvh];
        *(bfx4*)(Pw + ln * 40 + 16 + 4 * g) = pb4[2 * kvh + 1];
        asm volatile("s_waitcnt lgkmcnt(0)" ::: "memory");
        __builtin_amdgcn_sched_barrier(0);
        bfx8 pf = *(const bfx8*)(Pw + ln * 40 + g * 8);
        if (kvh == 0 && dorescale) {
#pragma unroll
          for (int dt = 0; dt < 8; ++dt) {
            o[dt][0] *= fr0; o[dt][1] *= fr1; o[dt][2] *= fr2; o[dt][3] *= fr3;
          }
        }
        __builtin_amdgcn_s_setprio(1);
#pragma unroll
        for (int dt = 0; dt < 8; ++dt) {
          bfx8 vf = *(const bfx8*)(lV0 + (dt * 16 + ln) * 128 +
                                   ((kvh * 64 + g * 16) ^ ((ln & 7) << 4)));
          o[dt] = __builtin_amdgcn_mfma_f32_16x16x32_bf16(pf, vf, o[dt], 0, 0, 0);
        }
        __builtin_amdgcn_s_setprio(0);
      }
    }
    __syncthreads();
  }

  float inv = 1.f / sum;
  float ir0 = __shfl(inv, 4 * g + 0);
  float ir1 = __shfl(inv, 4 * g + 1);
  float ir2 = __shfl(inv, 4 * g + 2);
  float ir3 = __shfl(inv, 4 * g + 3);
  const int b = bh >> 4, h = bh & 15;
  unsigned short* Ob = O + (size_t)b * LSEQ * HDIM + h * HD;
#pragma unroll
  for (int dt = 0; dt < 8; ++dt) {
    Ob[(size_t)(q0w + 4 * g + 0) * HDIM + dt * 16 + ln] = f2bf(o[dt][0] * ir0);
    Ob[(size_t)(q0w + 4 * g + 1) * HDIM + dt * 16 + ln] = f2bf(o[dt][1] * ir1);
    Ob[(size_t)(q0w + 4 * g + 2) * HDIM + dt * 16 + ln] = f2bf(o[dt][2] * ir2);
    Ob[(size_t)(q0w + 4 * g + 3) * HDIM + dt * 16 + ln] = f2bf(o[dt][3] * ir3);
  }
}

// ---------------- launch ----------------
extern "C" void kernel_launch(void* const* d_in, const int* in_sizes, int n_in,
                              void* d_out, int out_size, void* d_ws, size_t ws_size,
                              hipStream_t stream) {
  const float* x = (const float*)d_in[0];
  const float* w_qkv = (const float*)d_in[1];
  const float* w_o = (const float*)d_in[2];
  float* out = (float*)d_out;
  char* ws = (char*)d_ws;

  unsigned short* xb    = (unsigned short*)(ws + 0);
  unsigned short* wqkvb = (unsigned short*)(ws + 16777216);
  unsigned short* wob   = (unsigned short*)(ws + 41943040);
  unsigned short* qkvb  = (unsigned short*)(ws + 50331648);
  unsigned short* qb    = (unsigned short*)(ws + 100663296);
  unsigned short* kb    = (unsigned short*)(ws + 117440512);
  unsigned short* vtb   = (unsigned short*)(ws + 134217728);
  unsigned short* attnb = (unsigned short*)(ws + 0);

  cast_all_kernel<<<24576, 256, 0, stream>>>(x, w_qkv, w_o, xb, wqkvb, wob);

  // QKV: 128x192 tiles -> 32*32 = 1024 blocks = 2 rounds at 2 blocks/CU
  gemm128_kernel<192, true><<<(4096 / 128) * (6144 / 192), 512, 0, stream>>>(
      xb, wqkvb, (void*)qkvb, 4096, 6144, 2048);

  rope_scatter_kernel<<<dim3(32, 64), 256, 0, stream>>>(qkvb, qb, kb, vtb);

  flash_kernel<<<dim3(32, 16), 512, 0, stream>>>(qb, kb, vtb, attnb);

  // out-proj: 128x128 tiles -> 32*16 = 512 blocks = 1 round at 2 blocks/CU
  gemm128_kernel<128, false><<<(4096 / 128) * (2048 / 128), 512, 0, stream>>>(
      attnb, wob, (void*)out, 4096, 2048, 2048);
}

// Round 13
// 256.563 us; speedup vs baseline: 2.1783x; 1.0175x over previous
//
#include <hip/hip_runtime.h>

#define NHEADS 16
#define HD 128
#define LSEQ 2048
#define NBATCH 2
#define HDIM 2048
#define NQKV 6144
#define SCALE 0.08838834764831845f

typedef __attribute__((ext_vector_type(8))) short bfx8;
typedef __attribute__((ext_vector_type(4))) short bfx4;
typedef __attribute__((ext_vector_type(4))) float f32x4;

__device__ __forceinline__ unsigned short f2bf(float x) {
  unsigned u = __float_as_uint(x);
  u += 0x7fffu + ((u >> 16) & 1u);
  return (unsigned short)(u >> 16);
}
__device__ __forceinline__ float bf2f(unsigned short u) {
  return __uint_as_float(((unsigned)u) << 16);
}
__device__ __forceinline__ void gload_lds16(const void* g, void* l) {
  __builtin_amdgcn_global_load_lds(
      (const __attribute__((address_space(1))) unsigned int*)g,
      (__attribute__((address_space(3))) unsigned int*)l, 16, 0, 0);
}

// ---------------- fused cast f32 -> bf16 for x, w_qkv, w_o ----------------
__global__ __launch_bounds__(256) void cast_all_kernel(
    const float* __restrict__ x, const float* __restrict__ wq,
    const float* __restrict__ wo, unsigned short* __restrict__ xb,
    unsigned short* __restrict__ wqb, unsigned short* __restrict__ wob) {
  int i = blockIdx.x * 256 + threadIdx.x;
  const float* in;
  unsigned short* out;
  int li;
  if (i < 2097152) { in = x; out = xb; li = i; }
  else if (i < 2097152 + 3145728) { in = wq; out = wqb; li = i - 2097152; }
  else { in = wo; out = wob; li = i - (2097152 + 3145728); }
  float4 v = ((const float4*)in)[li];
  bfx4 o;
  o[0] = (short)f2bf(v.x);
  o[1] = (short)f2bf(v.y);
  o[2] = (short)f2bf(v.z);
  o[3] = (short)f2bf(v.w);
  ((bfx4*)out)[li] = o;
}

// ---------------- GEMM 128 x BN, BK=64, 4 waves (2Mx2N), barrier-light, 2 blocks/CU ----------------
// Wave-tile 64 x (NF*16): A-dup and B-dup both = 2 -> LDS reads cut ~25% vs the
// 8-wave 2Mx4N variant. 2 independent blocks/CU hide each other's tile drains.
template<int NF, bool BF16OUT>
__global__ __launch_bounds__(256, 2) void gemm4w_kernel(
    const unsigned short* __restrict__ A, const unsigned short* __restrict__ B,
    void* __restrict__ Cout, int M, int N, int K) {
  constexpr int BN = 2 * NF * 16;
  constexpr int BQ = BN / 32;          // B stage calls (32 rows each)
  __shared__ unsigned short lA[2][128 * 64];
  __shared__ unsigned short lB[2][BN * 64];
  const int tid = threadIdx.x;
  const int w = tid >> 6, lane = tid & 63;
  const int g = lane >> 4, ln = lane & 15;
  const int nmt = M >> 7, nnt = N / BN;
  const int nwg = nmt * nnt;
  const int bid = blockIdx.x;
  const int swz = (bid & 7) * (nwg >> 3) + (bid >> 3);  // nwg % 8 == 0
  const int bm = (swz / nnt) * 128, bn = (swz % nnt) * BN;
  const int wm = (w >> 1) * 64;
  const int wn = (w & 1) * (NF * 16);
  const unsigned short* At = A + (size_t)bm * K;
  const unsigned short* Bt = B + (size_t)bn * K;

  // stage 32 rows per call (8 rows/wave, 16B/lane, pre-swizzled source)
  auto STG = [&](const unsigned short* src, unsigned short* dst, int q, int k0) {
    int rid = q * 32 + w * 8 + (lane >> 3);
    int slot = lane & 7;
    gload_lds16(src + (size_t)rid * K + k0 + ((slot ^ (rid & 7)) << 3),
                dst + (size_t)(q * 2048 + w * 512));
  };
  auto STAGE_ALL = [&](int buf, int k0) {
#pragma unroll
    for (int q = 0; q < BQ; ++q) STG(Bt, lB[buf], q, k0);
#pragma unroll
    for (int q = 0; q < 4; ++q) STG(At, lA[buf], q, k0);
  };

  f32x4 acc[4][NF];
#pragma unroll
  for (int i = 0; i < 4; ++i)
#pragma unroll
    for (int j = 0; j < NF; ++j) acc[i][j] = (f32x4){0.f, 0.f, 0.f, 0.f};

  STAGE_ALL(0, 0);
  asm volatile("s_waitcnt vmcnt(0)" ::: "memory");
  __builtin_amdgcn_s_barrier();

  const int nt = K >> 6;
  for (int t = 0; t < nt; ++t) {
    const int cur = t & 1;
    const char* lAc = (const char*)lA[cur];
    const char* lBc = (const char*)lB[cur];
    const bool more = (t + 1 < nt);
    if (more) STAGE_ALL(cur ^ 1, (t + 1) << 6);

    bfx8 bfrag[NF][2];
#pragma unroll
    for (int nf = 0; nf < NF; ++nf)
#pragma unroll
      for (int kk = 0; kk < 2; ++kk)
        bfrag[nf][kk] = *(const bfx8*)(lBc + (wn + nf * 16 + ln) * 128 +
                                       (((kk * 4 + g) ^ (ln & 7)) << 4));
#pragma unroll
    for (int mf = 0; mf < 4; ++mf) {
      bfx8 afrag[2];
#pragma unroll
      for (int kk = 0; kk < 2; ++kk)
        afrag[kk] = *(const bfx8*)(lAc + (wm + mf * 16 + ln) * 128 +
                                   (((kk * 4 + g) ^ (ln & 7)) << 4));
#pragma unroll
      for (int kk = 0; kk < 2; ++kk)
#pragma unroll
        for (int nf = 0; nf < NF; ++nf)
          acc[mf][nf] = __builtin_amdgcn_mfma_f32_16x16x32_bf16(
              afrag[kk], bfrag[nf][kk], acc[mf][nf], 0, 0, 0);
    }

    asm volatile("s_waitcnt vmcnt(0)" ::: "memory");
    __builtin_amdgcn_s_barrier();
  }

#pragma unroll
  for (int mf = 0; mf < 4; ++mf) {
    int row0 = bm + wm + mf * 16 + g * 4;
#pragma unroll
    for (int nf = 0; nf < NF; ++nf) {
      int col = bn + wn + nf * 16 + ln;
#pragma unroll
      for (int r = 0; r < 4; ++r) {
        if constexpr (BF16OUT)
          ((unsigned short*)Cout)[(size_t)(row0 + r) * N + col] = f2bf(acc[mf][nf][r]);
        else
          ((float*)Cout)[(size_t)(row0 + r) * N + col] = acc[mf][nf][r];
      }
    }
  }
}

// ---------------- RoPE + scatter ----------------
__global__ __launch_bounds__(256) void rope_scatter_kernel(
    const unsigned short* __restrict__ qkv,
    unsigned short* __restrict__ Qo, unsigned short* __restrict__ Ko,
    unsigned short* __restrict__ Vt) {
  __shared__ unsigned short lV[32 * 128];
  const int bh = blockIdx.x;
  const int l0 = blockIdx.y * 32;
  const int b = bh >> 4, h = bh & 15;
  const int tid = threadIdx.x;
#pragma unroll
  for (int it = 0; it < 2; ++it) {
    int idx = it * 256 + tid;
    int ll = idx >> 4;
    int dq = idx & 15;
    int l = l0 + ll;
    const unsigned short* row = qkv + (size_t)(b * LSEQ + l) * NQKV + h * HD;
    bfx4 qlo = *(const bfx4*)(row + dq * 4);
    bfx4 qhi = *(const bfx4*)(row + 64 + dq * 4);
    bfx4 klo = *(const bfx4*)(row + 2048 + dq * 4);
    bfx4 khi = *(const bfx4*)(row + 2048 + 64 + dq * 4);
    bfx4 vlo = *(const bfx4*)(row + 4096 + dq * 4);
    bfx4 vhi = *(const bfx4*)(row + 4096 + 64 + dq * 4);
    bfx4 oqlo, oqhi, oklo, okhi;
#pragma unroll
    for (int e = 0; e < 4; ++e) {
      int d2 = dq * 4 + e;
      float invf = exp2f(-(float)d2 * 0.2076205059304601f);
      float fr = (float)l * invf;
      float s, c;
      sincosf(fr, &s, &c);
      float xq1 = bf2f((unsigned short)qlo[e]), xq2 = bf2f((unsigned short)qhi[e]);
      oqlo[e] = (short)f2bf(xq1 * c - xq2 * s);
      oqhi[e] = (short)f2bf(xq2 * c + xq1 * s);
      float xk1 = bf2f((unsigned short)klo[e]), xk2 = bf2f((unsigned short)khi[e]);
      oklo[e] = (short)f2bf(xk1 * c - xk2 * s);
      okhi[e] = (short)f2bf(xk2 * c + xk1 * s);
    }
    size_t obase = ((size_t)bh * LSEQ + l) * HD;
    *(bfx4*)(Qo + obase + dq * 4) = oqlo;
    *(bfx4*)(Qo + obase + 64 + dq * 4) = oqhi;
    *(bfx4*)(Ko + obase + dq * 4) = oklo;
    *(bfx4*)(Ko + obase + 64 + dq * 4) = okhi;
    *(bfx4*)(lV + ll * 128 + dq * 4) = vlo;
    *(bfx4*)(lV + ll * 128 + 64 + dq * 4) = vhi;
  }
  __syncthreads();
#pragma unroll
  for (int it = 0; it < 16; ++it) {
    int idx = it * 256 + tid;
    int d = idx >> 5;
    int ll = idx & 31;
    Vt[((size_t)bh * HD + d) * LSEQ + l0 + ll] = lV[ll * 128 + d];
  }
}

// ---------------- Flash attention: 8 waves, q-tile 128, KV chunk 64, LDS-staged ----------------
__global__ __launch_bounds__(512, 4) void flash_kernel(
    const unsigned short* __restrict__ Q, const unsigned short* __restrict__ K,
    const unsigned short* __restrict__ Vt, unsigned short* __restrict__ O) {
  __shared__ unsigned short lKs[2][64 * 128];
  __shared__ unsigned short lVs[2][128 * 64];
  __shared__ unsigned short lP[8][16 * 40];
  const int bh = blockIdx.x;
  const int qy = (int)blockIdx.y;
  const int qt = (qy < 8) ? (15 - qy) : (qy - 8);
  const int q0 = qt * 128;
  const int tid = threadIdx.x;
  const int w = tid >> 6, lane = tid & 63;
  const int g = lane >> 4, ln = lane & 15;
  const int q0w = q0 + w * 16;
  const unsigned short* Qb = Q + (size_t)bh * LSEQ * HD;
  const unsigned short* Kb = K + (size_t)bh * LSEQ * HD;
  const unsigned short* Vb = Vt + (size_t)bh * HD * LSEQ;
  unsigned short* Pw = lP[w];

  auto STAGE = [&](int buf, int kv0s) {
#pragma unroll
    for (int s = 0; s < 2; ++s) {
      int rl = s * 32 + w * 4 + (lane >> 4);
      int slot = lane & 15;
      const unsigned short* src =
          Kb + (size_t)(kv0s + rl) * HD + ((slot ^ (rl & 15)) * 8);
      gload_lds16(src, &lKs[buf][(s * 8192 + w * 1024) / 2]);
    }
#pragma unroll
    for (int s = 0; s < 2; ++s) {
      int d = s * 64 + w * 8 + (lane >> 3);
      int slot = lane & 7;
      const unsigned short* src =
          Vb + (size_t)d * LSEQ + kv0s + ((slot ^ (d & 7)) * 8);
      gload_lds16(src, &lVs[buf][(s * 8192 + w * 1024) / 2]);
    }
  };

  bfx8 qf[4];
#pragma unroll
  for (int c = 0; c < 4; ++c)
    qf[c] = *(const bfx8*)(Qb + (size_t)(q0w + ln) * HD + c * 32 + g * 8);

  f32x4 o[8];
#pragma unroll
  for (int dt = 0; dt < 8; ++dt) o[dt] = (f32x4){0.f, 0.f, 0.f, 0.f};
  float m = -1e30f, sum = 0.f;
  const int qg = q0w + ln;
  const int nch = 2 * qt + 2;

  STAGE(0, 0);
  __syncthreads();

  for (int ch = 0; ch < nch; ++ch) {
    const int kv0 = ch * 64;
    const int cur = ch & 1;
    if (ch + 1 < nch) STAGE(cur ^ 1, kv0 + 64);

    if (kv0 <= q0w + 15) {
      const char* lK0 = (const char*)lKs[cur];
      const char* lV0 = (const char*)lVs[cur];
      f32x4 s4[4];
#pragma unroll
      for (int kt = 0; kt < 4; ++kt) s4[kt] = (f32x4){0.f, 0.f, 0.f, 0.f};
      __builtin_amdgcn_s_setprio(1);
#pragma unroll
      for (int c = 0; c < 4; ++c) {
        const int cbb = c * 64 + g * 16;
#pragma unroll
        for (int kt = 0; kt < 4; ++kt) {
          bfx8 kf = *(const bfx8*)(lK0 + (kt * 16 + ln) * 256 + (cbb ^ (ln << 4)));
          s4[kt] = __builtin_amdgcn_mfma_f32_16x16x32_bf16(kf, qf[c], s4[kt], 0, 0, 0);
        }
      }
      __builtin_amdgcn_s_setprio(0);
      float tm = -1e30f;
      if (kv0 + 63 <= q0w) {
#pragma unroll
        for (int kt = 0; kt < 4; ++kt)
#pragma unroll
          for (int r = 0; r < 4; ++r) {
            s4[kt][r] *= SCALE;
            tm = fmaxf(tm, s4[kt][r]);
          }
      } else {
#pragma unroll
        for (int kt = 0; kt < 4; ++kt)
#pragma unroll
          for (int r = 0; r < 4; ++r) {
            int kvr = kv0 + kt * 16 + 4 * g + r;
            float v = (kvr <= qg) ? s4[kt][r] * SCALE : -1e30f;
            s4[kt][r] = v;
            tm = fmaxf(tm, v);
          }
      }
      tm = fmaxf(tm, __shfl_xor(tm, 16));
      tm = fmaxf(tm, __shfl_xor(tm, 32));
      float f = 1.f;
      const bool dorescale = !__all(tm <= m + 8.f);
      if (dorescale) {
        float mnew = fmaxf(m, tm);
        f = __expf(m - mnew);
        m = mnew;
      }
      float ts = 0.f;
      bfx4 pb4[4];
#pragma unroll
      for (int kt = 0; kt < 4; ++kt)
#pragma unroll
        for (int r = 0; r < 4; ++r) {
          float p = __expf(s4[kt][r] - m);
          ts += p;
          pb4[kt][r] = (short)f2bf(p);
        }
      ts += __shfl_xor(ts, 16);
      ts += __shfl_xor(ts, 32);
      sum = sum * f + ts;
      float fr0 = 1.f, fr1 = 1.f, fr2 = 1.f, fr3 = 1.f;
      if (dorescale) {
        fr0 = __shfl(f, 4 * g + 0);
        fr1 = __shfl(f, 4 * g + 1);
        fr2 = __shfl(f, 4 * g + 2);
        fr3 = __shfl(f, 4 * g + 3);
      }
#pragma unroll
      for (int kvh = 0; kvh < 2; ++kvh) {
        asm volatile("s_waitcnt lgkmcnt(0)" ::: "memory");
        __builtin_amdgcn_sched_barrier(0);
        *(bfx4*)(Pw + ln * 40 + 4 * g) = pb4[2 * kvh];
        *(bfx4*)(Pw + ln * 40 + 16 + 4 * g) = pb4[2 * kvh + 1];
        asm volatile("s_waitcnt lgkmcnt(0)" ::: "memory");
        __builtin_amdgcn_sched_barrier(0);
        bfx8 pf = *(const bfx8*)(Pw + ln * 40 + g * 8);
        if (kvh == 0 && dorescale) {
#pragma unroll
          for (int dt = 0; dt < 8; ++dt) {
            o[dt][0] *= fr0; o[dt][1] *= fr1; o[dt][2] *= fr2; o[dt][3] *= fr3;
          }
        }
        __builtin_amdgcn_s_setprio(1);
#pragma unroll
        for (int dt = 0; dt < 8; ++dt) {
          bfx8 vf = *(const bfx8*)(lV0 + (dt * 16 + ln) * 128 +
                                   ((kvh * 64 + g * 16) ^ ((ln & 7) << 4)));
          o[dt] = __builtin_amdgcn_mfma_f32_16x16x32_bf16(pf, vf, o[dt], 0, 0, 0);
        }
        __builtin_amdgcn_s_setprio(0);
      }
    }
    __syncthreads();
  }

  float inv = 1.f / sum;
  float ir0 = __shfl(inv, 4 * g + 0);
  float ir1 = __shfl(inv, 4 * g + 1);
  float ir2 = __shfl(inv, 4 * g + 2);
  float ir3 = __shfl(inv, 4 * g + 3);
  const int b = bh >> 4, h = bh & 15;
  unsigned short* Ob = O + (size_t)b * LSEQ * HDIM + h * HD;
#pragma unroll
  for (int dt = 0; dt < 8; ++dt) {
    Ob[(size_t)(q0w + 4 * g + 0) * HDIM + dt * 16 + ln] = f2bf(o[dt][0] * ir0);
    Ob[(size_t)(q0w + 4 * g + 1) * HDIM + dt * 16 + ln] = f2bf(o[dt][1] * ir1);
    Ob[(size_t)(q0w + 4 * g + 2) * HDIM + dt * 16 + ln] = f2bf(o[dt][2] * ir2);
    Ob[(size_t)(q0w + 4 * g + 3) * HDIM + dt * 16 + ln] = f2bf(o[dt][3] * ir3);
  }
}

// ---------------- launch ----------------
extern "C" void kernel_launch(void* const* d_in, const int* in_sizes, int n_in,
                              void* d_out, int out_size, void* d_ws, size_t ws_size,
                              hipStream_t stream) {
  const float* x = (const float*)d_in[0];
  const float* w_qkv = (const float*)d_in[1];
  const float* w_o = (const float*)d_in[2];
  float* out = (float*)d_out;
  char* ws = (char*)d_ws;

  unsigned short* xb    = (unsigned short*)(ws + 0);
  unsigned short* wqkvb = (unsigned short*)(ws + 16777216);
  unsigned short* wob   = (unsigned short*)(ws + 41943040);
  unsigned short* qkvb  = (unsigned short*)(ws + 50331648);
  unsigned short* qb    = (unsigned short*)(ws + 100663296);
  unsigned short* kb    = (unsigned short*)(ws + 117440512);
  unsigned short* vtb   = (unsigned short*)(ws + 134217728);
  unsigned short* attnb = (unsigned short*)(ws + 0);

  cast_all_kernel<<<24576, 256, 0, stream>>>(x, w_qkv, w_o, xb, wqkvb, wob);

  // QKV: 128x192 tiles -> 32*32 = 1024 blocks, 256 thr, 2 blocks/CU
  gemm4w_kernel<6, true><<<(4096 / 128) * (6144 / 192), 256, 0, stream>>>(
      xb, wqkvb, (void*)qkvb, 4096, 6144, 2048);

  rope_scatter_kernel<<<dim3(32, 64), 256, 0, stream>>>(qkvb, qb, kb, vtb);

  flash_kernel<<<dim3(32, 16), 512, 0, stream>>>(qb, kb, vtb, attnb);

  // out-proj: 128x128 tiles -> 32*16 = 512 blocks, 256 thr, 2 blocks/CU
  gemm4w_kernel<4, false><<<(4096 / 128) * (2048 / 128), 256, 0, stream>>>(
      attnb, wob, (void*)out, 4096, 2048, 2048);
}